// Round 2
// baseline (590.851 us; speedup 1.0000x reference)
//
#include <hip/hip_runtime.h>
#include <stdint.h>

#define DD 1024
#define TT 2048
#define BBATCH 8
#define MM (BBATCH*TT)   // 16384 rows

typedef unsigned short u16;
typedef unsigned int   u32;

typedef __attribute__((ext_vector_type(8))) __bf16 bf16x8;
typedef __attribute__((ext_vector_type(4))) float  floatx4;
typedef __attribute__((ext_vector_type(4))) unsigned short u16x4;

__device__ __forceinline__ float b2f(u16 v){
    u32 x = ((u32)v) << 16;
    return __builtin_bit_cast(float, x);
}
__device__ __forceinline__ u16 f2b(float f){
    u32 u = __builtin_bit_cast(u32, f);
    u32 r = (u + 0x7fffu + ((u >> 16) & 1u)) >> 16;
    return (u16)r;
}
__device__ __forceinline__ float sigf(float x){
    return 1.0f / (1.0f + __expf(-x));
}
__device__ __forceinline__ float tanhfast(float x){
    float e = __expf(2.0f * x);          // inf for big x -> 1.0 (correct limit)
    return 1.0f - 2.0f / (e + 1.0f);
}

// async global->LDS, 16B per lane. LDS dest = wave-uniform base + lane*16.
__device__ __forceinline__ void g2l16(const u16* g, u16* l){
    __builtin_amdgcn_global_load_lds(
        (const __attribute__((address_space(1))) u32*)g,
        (__attribute__((address_space(3))) u32*)l, 16, 0, 0);
}

__device__ __forceinline__ void load4bf(const u16* p, float* o){
    u16x4 v = *(const u16x4*)p;
    o[0] = b2f(v.x); o[1] = b2f(v.y); o[2] = b2f(v.z); o[3] = b2f(v.w);
}

__device__ __forceinline__ void block_reduce2(float& a, float& b, float* red, int tid){
    #pragma unroll
    for (int off = 32; off; off >>= 1){
        a += __shfl_down(a, off, 64);
        b += __shfl_down(b, off, 64);
    }
    __syncthreads();                      // protect red from previous round
    if ((tid & 63) == 0){ red[tid >> 6] = a; red[4 + (tid >> 6)] = b; }
    __syncthreads();
    a = red[0] + red[1] + red[2] + red[3];
    b = red[4] + red[5] + red[6] + red[7];
}

// ---------------- fp32 -> bf16 bulk convert ----------------
__global__ __launch_bounds__(256) void cvt_f2b(
    const float* __restrict__ in, u16* __restrict__ out)
{
    const size_t i = ((size_t)blockIdx.x * 256 + threadIdx.x) * 4;
    floatx4 v = *(const floatx4*)(in + i);
    u16x4 o;
    o.x = f2b(v.x); o.y = f2b(v.y); o.z = f2b(v.z); o.w = f2b(v.w);
    *(u16x4*)(out + i) = o;
}

// ---------------- weight transpose: 6 x [1024,1024] fp32 -> bf16 [N,K] ----------------
__global__ __launch_bounds__(256) void transpose_w(
    const float* __restrict__ s0, const float* __restrict__ s1, const float* __restrict__ s2,
    const float* __restrict__ s3, const float* __restrict__ s4, const float* __restrict__ s5,
    u16* __restrict__ dst_base)
{
    __shared__ u16 tile[32][33];
    const float* srcs[6] = {s0, s1, s2, s3, s4, s5};
    const int z = blockIdx.z;
    const float* src = srcs[z];
    u16* dst = dst_base + (size_t)z * (DD * (size_t)DD);
    const int tx = threadIdx.x, ty = threadIdx.y;
    const int x = blockIdx.x * 32 + tx;
    #pragma unroll
    for (int i = 0; i < 4; i++){
        int y = blockIdx.y * 32 + ty + i * 8;
        tile[ty + i * 8][tx] = f2b(src[(size_t)y * DD + x]);
    }
    __syncthreads();
    const int x2 = blockIdx.y * 32 + tx;
    #pragma unroll
    for (int i = 0; i < 4; i++){
        int y2 = blockIdx.x * 32 + ty + i * 8;
        dst[(size_t)y2 * DD + x2] = tile[tx][ty + i * 8];
    }
}

// ---------------- row-wise zero-centered RMS norm (fp32 in, bf16 out) ----------------
__global__ __launch_bounds__(256) void zcrms_rows(
    const float* __restrict__ in, const float* __restrict__ g, u16* __restrict__ out)
{
    __shared__ float red[8];
    const int row = blockIdx.x, tid = threadIdx.x;
    const int d0 = tid * 4;
    const size_t base = (size_t)row * DD + d0;
    floatx4 v = *(const floatx4*)(in + base);
    float s1 = v.x + v.y + v.z + v.w;
    float s2 = v.x*v.x + v.y*v.y + v.z*v.z + v.w*v.w;
    block_reduce2(s1, s2, red, tid);
    float mu = s1 * (1.0f / DD);
    float ms = fmaxf(s2 * (1.0f / DD) - mu * mu, 0.0f);
    float sc = rsqrtf(ms + 1e-8f);
    floatx4 gv = *(const floatx4*)(g + d0);
    u16x4 ov;
    ov.x = f2b((v.x - mu) * sc * gv.x);
    ov.y = f2b((v.y - mu) * sc * gv.y);
    ov.z = f2b((v.z - mu) * sc * gv.z);
    ov.w = f2b((v.w - mu) * sc * gv.w);
    *(u16x4*)(out + base) = ov;
}

// ---------------- GEMM: C[M,N] = A[M,K](bf16) * W^T[N,K](bf16)^T + bias(fp32) ----------------
struct GemmPtrs {
    const u16*   A[5];
    const u16*   W[5];     // transposed weights, [N,K] row-major, bf16
    const float* bias[5];
    u16*         out[5];
};

template<int MODE>   // 0: store bf16(A*W+bias) ; 1: fp32 epilogue with residual
__global__ __launch_bounds__(256) void gemm_bf16(
    GemmPtrs ptrs, const float* __restrict__ xres, float* __restrict__ dout)
{
    constexpr int BK = 32;
    __shared__ alignas(16) u16 As[128 * BK];
    __shared__ alignas(16) u16 Bs[128 * BK];

    const int z = blockIdx.z;
    const u16*   __restrict__ A    = ptrs.A[z];
    const u16*   __restrict__ W    = ptrs.W[z];
    const float* __restrict__ bias = ptrs.bias[z];
    u16* __restrict__ Cout = ptrs.out[z];

    const int tid  = threadIdx.x;
    const int wave = tid >> 6, lane = tid & 63;
    const int quad = lane >> 4, l16 = lane & 15;
    const int bm = blockIdx.y * 128;
    const int bn = blockIdx.x * 128;
    const int wm = (wave & 1) * 64, wn = (wave >> 1) * 64;

    // staging: 512 chunks of 16B per tile (128 rows x 4 k-chunks); 2 chunks/thread/tile
    const int c0 = tid, c1 = tid + 256;
    const int r0 = c0 >> 2, kc0 = (c0 & 3) * 8;
    const int r1 = c1 >> 2, kc1 = (c1 & 3) * 8;
    const u16* a0p = A + (size_t)(bm + r0) * DD + kc0;
    const u16* a1p = A + (size_t)(bm + r1) * DD + kc1;
    const u16* w0p = W + (size_t)(bn + r0) * DD + kc0;
    const u16* w1p = W + (size_t)(bn + r1) * DD + kc1;

    floatx4 acc[4][4];
    #pragma unroll
    for (int i = 0; i < 4; i++)
        #pragma unroll
        for (int j = 0; j < 4; j++)
            acc[i][j] = (floatx4){0.f, 0.f, 0.f, 0.f};

    for (int k0 = 0; k0 < DD; k0 += BK){
        g2l16(a0p + k0, &As[c0 * 8]);
        g2l16(a1p + k0, &As[c1 * 8]);
        g2l16(w0p + k0, &Bs[c0 * 8]);
        g2l16(w1p + k0, &Bs[c1 * 8]);
        __syncthreads();
        bf16x8 af[4], bfr[4];
        #pragma unroll
        for (int i = 0; i < 4; i++){
            af[i]  = *(const bf16x8*)&As[(wm + i * 16 + l16) * BK + quad * 8];
            bfr[i] = *(const bf16x8*)&Bs[(wn + i * 16 + l16) * BK + quad * 8];
        }
        #pragma unroll
        for (int i = 0; i < 4; i++)
            #pragma unroll
            for (int j = 0; j < 4; j++)
                acc[i][j] = __builtin_amdgcn_mfma_f32_16x16x32_bf16(af[i], bfr[j], acc[i][j], 0, 0, 0);
        __syncthreads();
    }

    float bj[4];
    #pragma unroll
    for (int j = 0; j < 4; j++) bj[j] = bias[bn + wn + j * 16 + l16];

    #pragma unroll
    for (int i = 0; i < 4; i++){
        const int rbase = bm + wm + i * 16 + quad * 4;
        #pragma unroll
        for (int j = 0; j < 4; j++){
            const int col = bn + wn + j * 16 + l16;
            #pragma unroll
            for (int r = 0; r < 4; r++){
                size_t idx = (size_t)(rbase + r) * DD + col;
                float zv = acc[i][j][r] + bj[j];
                if (MODE == 0){
                    Cout[idx] = f2b(zv);
                } else {
                    float sl = zv * sigf(zv);            // silu(dhat)
                    dout[idx] = xres[idx] + sigf(sl) * zv;
                }
            }
        }
    }
}

// ---------------- fused middle: dwconv3+sigmoid, l2norm, delta, gate-mix, zc_rms ----------------
__global__ __launch_bounds__(256) void mid_fuse(
    const u16* __restrict__ q0, const u16* __restrict__ k0, const u16* __restrict__ v0,
    const u16* __restrict__ a0, const u16* __restrict__ b0,
    const float* __restrict__ wqc, const float* __restrict__ bqc,
    const float* __restrict__ wkc, const float* __restrict__ bkc,
    const float* __restrict__ wvc, const float* __restrict__ bvc,
    const float* __restrict__ g2, u16* __restrict__ uout)
{
    __shared__ float red[8];
    const int row = blockIdx.x;
    const int t   = row & (TT - 1);
    const int tid = threadIdx.x;
    const int d0  = tid * 4;
    const size_t base = (size_t)row * DD + d0;
    const bool hm = (t > 0), hp = (t < TT - 1);

    float q[4], k[4], v[4];
    {
        const u16*   srcs[3] = {q0, k0, v0};
        const float* ws[3]   = {wqc, wkc, wvc};
        const float* bs[3]   = {bqc, bkc, bvc};
        float* outs[3]       = {q, k, v};
        #pragma unroll
        for (int s = 0; s < 3; s++){
            float cm[4], cc[4], cp[4];
            load4bf(srcs[s] + base, cc);
            if (hm) load4bf(srcs[s] + base - DD, cm); else { cm[0]=cm[1]=cm[2]=cm[3]=0.f; }
            if (hp) load4bf(srcs[s] + base + DD, cp); else { cp[0]=cp[1]=cp[2]=cp[3]=0.f; }
            #pragma unroll
            for (int j = 0; j < 4; j++){
                int d = d0 + j;
                float y = cm[j] * ws[s][d * 3 + 0]
                        + cc[j] * ws[s][d * 3 + 1]
                        + cp[j] * ws[s][d * 3 + 2]
                        + bs[s][d];
                outs[s][j] = sigf(y);
            }
        }
    }

    float sq = 0.f, sk = 0.f;
    #pragma unroll
    for (int j = 0; j < 4; j++){ sq += q[j] * q[j]; sk += k[j] * k[j]; }
    block_reduce2(sq, sk, red, tid);
    const float rq = rsqrtf(sq + 1e-8f), rk = rsqrtf(sk + 1e-8f);

    float av[4], bv[4];
    load4bf(a0 + base, av);
    load4bf(b0 + base, bv);

    float dl[4], s1 = 0.f, s2 = 0.f;
    #pragma unroll
    for (int j = 0; j < 4; j++){
        float d = (q[j] * rq) * (k[j] * rk) * v[j];
        d = tanhfast(av[j]) * d + bv[j];
        dl[j] = d; s1 += d; s2 += d * d;
    }
    block_reduce2(s1, s2, red, tid);
    const float mu = s1 * (1.0f / DD);
    const float ms = fmaxf(s2 * (1.0f / DD) - mu * mu, 0.0f);
    const float sc = rsqrtf(ms + 1e-8f);

    u16x4 ov;
    ov.x = f2b((dl[0] - mu) * sc * g2[d0 + 0]);
    ov.y = f2b((dl[1] - mu) * sc * g2[d0 + 1]);
    ov.z = f2b((dl[2] - mu) * sc * g2[d0 + 2]);
    ov.w = f2b((dl[3] - mu) * sc * g2[d0 + 3]);
    *(u16x4*)(uout + base) = ov;
}

extern "C" void kernel_launch(void* const* d_in, const int* in_sizes, int n_in,
                              void* d_out, int out_size, void* d_ws, size_t ws_size,
                              hipStream_t stream)
{
    const float* x   = (const float*)d_in[0];
    const float* g1  = (const float*)d_in[1];
    const float* Wq  = (const float*)d_in[2];
    const float* bq  = (const float*)d_in[3];
    const float* Wk  = (const float*)d_in[4];
    const float* bk  = (const float*)d_in[5];
    const float* Wv  = (const float*)d_in[6];
    const float* bv  = (const float*)d_in[7];
    const float* wqc = (const float*)d_in[8];
    const float* bqc = (const float*)d_in[9];
    const float* wkc = (const float*)d_in[10];
    const float* bkc = (const float*)d_in[11];
    const float* wvc = (const float*)d_in[12];
    const float* bvc = (const float*)d_in[13];
    const float* Wa  = (const float*)d_in[14];
    const float* ba  = (const float*)d_in[15];
    const float* Wb  = (const float*)d_in[16];
    const float* bb  = (const float*)d_in[17];
    const float* g2  = (const float*)d_in[18];
    const float* Wp  = (const float*)d_in[19];
    const float* bp  = (const float*)d_in[20];

    u16* ws = (u16*)d_ws;
    const size_t WSZ = (size_t)DD * DD;      // 1M elements
    const size_t TSZ = (size_t)MM * DD;      // 16.78M elements
    u16* WT = ws;                             // 6 transposed bf16 weights (q,k,v,a,b,p)
    u16* xb = ws + 6 * WSZ;                   // bf16 copy of x
    u16* h  = xb + TSZ;
    u16* q0 = h  + TSZ;
    u16* k0 = q0 + TSZ;
    u16* v0 = k0 + TSZ;
    u16* a0 = v0 + TSZ;
    u16* b0 = a0 + TSZ;
    u16* u  = h;                              // h dead after GEMM stage; reuse for u

    transpose_w<<<dim3(32, 32, 6), dim3(32, 8, 1), 0, stream>>>(Wq, Wk, Wv, Wa, Wb, Wp, WT);
    cvt_f2b<<<dim3(TSZ / 1024), dim3(256), 0, stream>>>(x, xb);
    zcrms_rows<<<dim3(MM), dim3(256), 0, stream>>>(x, g1, h);

    GemmPtrs p0;
    p0.A[0] = h;  p0.W[0] = WT + 0 * WSZ; p0.bias[0] = bq; p0.out[0] = q0;
    p0.A[1] = h;  p0.W[1] = WT + 1 * WSZ; p0.bias[1] = bk; p0.out[1] = k0;
    p0.A[2] = h;  p0.W[2] = WT + 2 * WSZ; p0.bias[2] = bv; p0.out[2] = v0;
    p0.A[3] = xb; p0.W[3] = WT + 3 * WSZ; p0.bias[3] = ba; p0.out[3] = a0;
    p0.A[4] = xb; p0.W[4] = WT + 4 * WSZ; p0.bias[4] = bb; p0.out[4] = b0;
    gemm_bf16<0><<<dim3(8, 128, 5), dim3(256), 0, stream>>>(p0, nullptr, nullptr);

    mid_fuse<<<dim3(MM), dim3(256), 0, stream>>>(q0, k0, v0, a0, b0,
                                                 wqc, bqc, wkc, bkc, wvc, bvc, g2, u);

    GemmPtrs p1;
    for (int i = 0; i < 5; i++){ p1.A[i] = u; p1.W[i] = WT + 5 * WSZ; p1.bias[i] = bp; p1.out[i] = nullptr; }
    gemm_bf16<1><<<dim3(8, 128, 1), dim3(256), 0, stream>>>(p1, x, (float*)d_out);
}

// Round 4
// 571.526 us; speedup vs baseline: 1.0338x; 1.0338x over previous
//
#include <hip/hip_runtime.h>
#include <stdint.h>

#define DD 1024
#define TT 2048
#define BBATCH 8
#define MM (BBATCH*TT)   // 16384 rows

typedef unsigned short u16;
typedef unsigned int   u32;

typedef __attribute__((ext_vector_type(8))) __bf16 bf16x8;
typedef __attribute__((ext_vector_type(4))) float  floatx4;
typedef __attribute__((ext_vector_type(4))) unsigned short u16x4;
typedef __attribute__((ext_vector_type(8))) unsigned short u16x8;

__device__ __forceinline__ float b2f(u16 v){
    u32 x = ((u32)v) << 16;
    return __builtin_bit_cast(float, x);
}
__device__ __forceinline__ u16 f2b(float f){
    u32 u = __builtin_bit_cast(u32, f);
    u32 r = (u + 0x7fffu + ((u >> 16) & 1u)) >> 16;
    return (u16)r;
}
__device__ __forceinline__ float sigf(float x){
    return 1.0f / (1.0f + __expf(-x));
}
__device__ __forceinline__ float tanhfast(float x){
    float e = __expf(2.0f * x);          // inf for big x -> 1.0 (correct limit)
    return 1.0f - 2.0f / (e + 1.0f);
}

// async global->LDS, 16B per lane. LDS dest = wave-uniform base + lane*16.
__device__ __forceinline__ void g2l16(const u16* g, u16* l){
    __builtin_amdgcn_global_load_lds(
        (const __attribute__((address_space(1))) u32*)g,
        (__attribute__((address_space(3))) u32*)l, 16, 0, 0);
}

__device__ __forceinline__ void load16bf(const u16* p, float* o){
    u16x8 a = *(const u16x8*)p;
    u16x8 b = *(const u16x8*)(p + 8);
    #pragma unroll
    for (int j = 0; j < 8; j++) o[j]     = b2f(a[j]);
    #pragma unroll
    for (int j = 0; j < 8; j++) o[8 + j] = b2f(b[j]);
}

__device__ __forceinline__ void zero16(float* o){
    #pragma unroll
    for (int j = 0; j < 16; j++) o[j] = 0.f;
}

__device__ __forceinline__ void wave_reduce2(float& a, float& b){
    #pragma unroll
    for (int m = 32; m; m >>= 1){
        a += __shfl_xor(a, m, 64);
        b += __shfl_xor(b, m, 64);
    }
}

__device__ __forceinline__ void block_reduce2(float& a, float& b, float* red, int tid){
    #pragma unroll
    for (int off = 32; off; off >>= 1){
        a += __shfl_down(a, off, 64);
        b += __shfl_down(b, off, 64);
    }
    if ((tid & 63) == 0){ red[tid >> 6] = a; red[4 + (tid >> 6)] = b; }
    __syncthreads();
    a = red[0] + red[1] + red[2] + red[3];
    b = red[4] + red[5] + red[6] + red[7];
}

// ---------------- weight transpose: 6 x [1024,1024] fp32 -> bf16 [N,K] ----------------
__global__ __launch_bounds__(256) void transpose_w(
    const float* __restrict__ s0, const float* __restrict__ s1, const float* __restrict__ s2,
    const float* __restrict__ s3, const float* __restrict__ s4, const float* __restrict__ s5,
    u16* __restrict__ dst_base)
{
    __shared__ u16 tile[32][33];
    const float* srcs[6] = {s0, s1, s2, s3, s4, s5};
    const int z = blockIdx.z;
    const float* src = srcs[z];
    u16* dst = dst_base + (size_t)z * (DD * (size_t)DD);
    const int tx = threadIdx.x, ty = threadIdx.y;
    const int x = blockIdx.x * 32 + tx;
    #pragma unroll
    for (int i = 0; i < 4; i++){
        int y = blockIdx.y * 32 + ty + i * 8;
        tile[ty + i * 8][tx] = f2b(src[(size_t)y * DD + x]);
    }
    __syncthreads();
    const int x2 = blockIdx.y * 32 + tx;
    #pragma unroll
    for (int i = 0; i < 4; i++){
        int y2 = blockIdx.x * 32 + ty + i * 8;
        dst[(size_t)y2 * DD + x2] = tile[tx][ty + i * 8];
    }
}

// ---------------- conv-weight transpose: [1024,3] -> [3][1024], 3 streams ----------------
__global__ __launch_bounds__(256) void prep_wc(
    const float* __restrict__ w0, const float* __restrict__ w1, const float* __restrict__ w2,
    float* __restrict__ wcT)
{
    const float* srcs[3] = {w0, w1, w2};
    const int s = blockIdx.x / 3, tap = blockIdx.x % 3;
    #pragma unroll
    for (int i = 0; i < 4; i++){
        int d = threadIdx.x + i * 256;
        wcT[(s * 3 + tap) * DD + d] = srcs[s][d * 3 + tap];
    }
}

// ---------------- fused: x -> bf16 copy (xb) + zc_rms(x,g1) -> h (bf16) ----------------
__global__ __launch_bounds__(256) void prep_rows(
    const float* __restrict__ in, const float* __restrict__ g,
    u16* __restrict__ xb, u16* __restrict__ h)
{
    __shared__ float red[8];
    const int row = blockIdx.x, tid = threadIdx.x;
    const int d0 = tid * 4;
    const size_t base = (size_t)row * DD + d0;
    floatx4 v = *(const floatx4*)(in + base);
    u16x4 xv;
    xv.x = f2b(v.x); xv.y = f2b(v.y); xv.z = f2b(v.z); xv.w = f2b(v.w);
    *(u16x4*)(xb + base) = xv;
    float s1 = v.x + v.y + v.z + v.w;
    float s2 = v.x*v.x + v.y*v.y + v.z*v.z + v.w*v.w;
    block_reduce2(s1, s2, red, tid);
    float mu = s1 * (1.0f / DD);
    float ms = fmaxf(s2 * (1.0f / DD) - mu * mu, 0.0f);
    float sc = rsqrtf(ms + 1e-8f);
    floatx4 gv = *(const floatx4*)(g + d0);
    u16x4 ov;
    ov.x = f2b((v.x - mu) * sc * gv.x);
    ov.y = f2b((v.y - mu) * sc * gv.y);
    ov.z = f2b((v.z - mu) * sc * gv.z);
    ov.w = f2b((v.w - mu) * sc * gv.w);
    *(u16x4*)(h + base) = ov;
}

// ---------------- GEMM: C[M,N] = A[M,K](bf16) * W^T[N,K](bf16)^T + bias(fp32) ----------------
struct GemmPtrs {
    const u16*   A[5];
    const u16*   W[5];     // transposed weights, [N,K] row-major, bf16
    const float* bias[5];
    u16*         out[5];
};

template<int MODE>   // 0: store bf16(A*W+bias) ; 1: fp32 epilogue with residual
__global__ __launch_bounds__(256) void gemm_bf16(
    GemmPtrs ptrs, const float* __restrict__ xres, float* __restrict__ dout)
{
    constexpr int BK = 32;
    __shared__ alignas(16) u16 As[128 * BK];
    __shared__ alignas(16) u16 Bs[128 * BK];

    const int z = blockIdx.z;
    const u16*   __restrict__ A    = ptrs.A[z];
    const u16*   __restrict__ W    = ptrs.W[z];
    const float* __restrict__ bias = ptrs.bias[z];
    u16* __restrict__ Cout = ptrs.out[z];

    const int tid  = threadIdx.x;
    const int wave = tid >> 6, lane = tid & 63;
    const int quad = lane >> 4, l16 = lane & 15;
    // XCD swizzle: bm is the fastest-varying grid dim, so the 8 blocks sharing
    // one A row-tile (all bn at fixed bm) spread bm%8 across XCDs -> each A
    // tile is resident in exactly one per-XCD L2 instead of all eight.
    const int bm = blockIdx.x * 128;
    const int bn = blockIdx.y * 128;
    const int wm = (wave & 1) * 64, wn = (wave >> 1) * 64;

    // staging: 1024 chunks of 16B per (A,B) tile pair; 4 chunks/thread
    const int c0 = tid, c1 = tid + 256;
    const int r0 = c0 >> 2, kc0 = (c0 & 3) * 8;
    const int r1 = c1 >> 2, kc1 = (c1 & 3) * 8;
    const u16* a0p = A + (size_t)(bm + r0) * DD + kc0;
    const u16* a1p = A + (size_t)(bm + r1) * DD + kc1;
    const u16* w0p = W + (size_t)(bn + r0) * DD + kc0;
    const u16* w1p = W + (size_t)(bn + r1) * DD + kc1;

    floatx4 acc[4][4];
    #pragma unroll
    for (int i = 0; i < 4; i++)
        #pragma unroll
        for (int j = 0; j < 4; j++)
            acc[i][j] = (floatx4){0.f, 0.f, 0.f, 0.f};

    for (int k0 = 0; k0 < DD; k0 += BK){
        g2l16(a0p + k0, &As[c0 * 8]);
        g2l16(a1p + k0, &As[c1 * 8]);
        g2l16(w0p + k0, &Bs[c0 * 8]);
        g2l16(w1p + k0, &Bs[c1 * 8]);
        __syncthreads();
        bf16x8 af[4], bfr[4];
        #pragma unroll
        for (int i = 0; i < 4; i++){
            af[i]  = *(const bf16x8*)&As[(wm + i * 16 + l16) * BK + quad * 8];
            bfr[i] = *(const bf16x8*)&Bs[(wn + i * 16 + l16) * BK + quad * 8];
        }
        #pragma unroll
        for (int i = 0; i < 4; i++)
            #pragma unroll
            for (int j = 0; j < 4; j++)
                acc[i][j] = __builtin_amdgcn_mfma_f32_16x16x32_bf16(af[i], bfr[j], acc[i][j], 0, 0, 0);
        __syncthreads();
    }

    float bj[4];
    #pragma unroll
    for (int j = 0; j < 4; j++) bj[j] = bias[bn + wn + j * 16 + l16];

    #pragma unroll
    for (int i = 0; i < 4; i++){
        const int rbase = bm + wm + i * 16 + quad * 4;
        #pragma unroll
        for (int j = 0; j < 4; j++){
            const int col = bn + wn + j * 16 + l16;
            #pragma unroll
            for (int r = 0; r < 4; r++){
                size_t idx = (size_t)(rbase + r) * DD + col;
                float zv = acc[i][j][r] + bj[j];
                if (MODE == 0){
                    Cout[idx] = f2b(zv);
                } else {
                    float sl = zv * sigf(zv);            // silu(dhat)
                    dout[idx] = xres[idx] + sigf(sl) * zv;
                }
            }
        }
    }
}

// ---------------- fused middle: one row per wave, no LDS / no syncthreads ----------------
__global__ __launch_bounds__(256) void mid_fuse(
    const u16* __restrict__ q0, const u16* __restrict__ k0, const u16* __restrict__ v0,
    const u16* __restrict__ a0, const u16* __restrict__ b0,
    const float* __restrict__ wcT,     // [3 streams][3 taps][1024]
    const float* __restrict__ bqc, const float* __restrict__ bkc, const float* __restrict__ bvc,
    const float* __restrict__ g2, u16* __restrict__ uout)
{
    const int tid  = threadIdx.x;
    const int w    = tid >> 6, lane = tid & 63;
    const int row  = blockIdx.x * 4 + w;
    const int t    = row & (TT - 1);
    const int d0   = lane * 16;
    const size_t base = (size_t)row * DD + d0;
    const bool hm = (t > 0), hp = (t < TT - 1);

    float q[16], k[16], v[16];
    {
        const u16*   srcs[3] = {q0, k0, v0};
        const float* bs[3]   = {bqc, bkc, bvc};
        float* outs[3]       = {q, k, v};
        #pragma unroll
        for (int s = 0; s < 3; s++){
            float cm[16], cc[16], cp[16];
            load16bf(srcs[s] + base, cc);
            if (hm) load16bf(srcs[s] + base - DD, cm);
            else    zero16(cm);
            if (hp) load16bf(srcs[s] + base + DD, cp);
            else    zero16(cp);
            const float* wt = wcT + s * 3 * DD + d0;
            const float* bb = bs[s] + d0;
            #pragma unroll
            for (int j = 0; j < 16; j++){
                float y = cm[j] * wt[j] + cc[j] * wt[DD + j] + cp[j] * wt[2 * DD + j] + bb[j];
                outs[s][j] = sigf(y);
            }
        }
    }

    float sq = 0.f, sk = 0.f;
    #pragma unroll
    for (int j = 0; j < 16; j++){ sq += q[j] * q[j]; sk += k[j] * k[j]; }
    wave_reduce2(sq, sk);
    const float rq = rsqrtf(sq + 1e-8f), rk = rsqrtf(sk + 1e-8f);

    float av[16], bv[16];
    load16bf(a0 + base, av);
    load16bf(b0 + base, bv);

    float dl[16], s1 = 0.f, s2 = 0.f;
    #pragma unroll
    for (int j = 0; j < 16; j++){
        float d = (q[j] * rq) * (k[j] * rk) * v[j];
        d = tanhfast(av[j]) * d + bv[j];
        dl[j] = d; s1 += d; s2 += d * d;
    }
    wave_reduce2(s1, s2);
    const float mu = s1 * (1.0f / DD);
    const float ms = fmaxf(s2 * (1.0f / DD) - mu * mu, 0.0f);
    const float sc = rsqrtf(ms + 1e-8f);

    u16x8 o0, o1;
    #pragma unroll
    for (int j = 0; j < 8; j++)  o0[j] = f2b((dl[j] - mu) * sc * g2[d0 + j]);
    #pragma unroll
    for (int j = 0; j < 8; j++)  o1[j] = f2b((dl[8 + j] - mu) * sc * g2[d0 + 8 + j]);
    *(u16x8*)(uout + base)     = o0;
    *(u16x8*)(uout + base + 8) = o1;
}

extern "C" void kernel_launch(void* const* d_in, const int* in_sizes, int n_in,
                              void* d_out, int out_size, void* d_ws, size_t ws_size,
                              hipStream_t stream)
{
    const float* x   = (const float*)d_in[0];
    const float* g1  = (const float*)d_in[1];
    const float* Wq  = (const float*)d_in[2];
    const float* bq  = (const float*)d_in[3];
    const float* Wk  = (const float*)d_in[4];
    const float* bk  = (const float*)d_in[5];
    const float* Wv  = (const float*)d_in[6];
    const float* bv  = (const float*)d_in[7];
    const float* wqc = (const float*)d_in[8];
    const float* bqc = (const float*)d_in[9];
    const float* wkc = (const float*)d_in[10];
    const float* bkc = (const float*)d_in[11];
    const float* wvc = (const float*)d_in[12];
    const float* bvc = (const float*)d_in[13];
    const float* Wa  = (const float*)d_in[14];
    const float* ba  = (const float*)d_in[15];
    const float* Wb  = (const float*)d_in[16];
    const float* bb  = (const float*)d_in[17];
    const float* g2  = (const float*)d_in[18];
    const float* Wp  = (const float*)d_in[19];
    const float* bp  = (const float*)d_in[20];

    u16* ws = (u16*)d_ws;
    const size_t WSZ = (size_t)DD * DD;      // 1M elements
    const size_t TSZ = (size_t)MM * DD;      // 16.78M elements
    u16* WT = ws;                             // 6 transposed bf16 weights (q,k,v,a,b,p)
    float* wcT = (float*)(ws + 6 * WSZ);      // 3*3*1024 fp32 conv weights, transposed
    u16* xb = ws + 6 * WSZ + 32768;           // bf16 copy of x (64KB gap holds wcT)
    u16* h  = xb + TSZ;
    u16* q0 = h  + TSZ;
    u16* k0 = q0 + TSZ;
    u16* v0 = k0 + TSZ;
    u16* a0 = v0 + TSZ;
    u16* b0 = a0 + TSZ;
    u16* u  = h;                              // h dead after GEMM stage; reuse for u

    transpose_w<<<dim3(32, 32, 6), dim3(32, 8, 1), 0, stream>>>(Wq, Wk, Wv, Wa, Wb, Wp, WT);
    prep_wc<<<dim3(9), dim3(256), 0, stream>>>(wqc, wkc, wvc, wcT);
    prep_rows<<<dim3(MM), dim3(256), 0, stream>>>(x, g1, xb, h);

    GemmPtrs p0;
    p0.A[0] = h;  p0.W[0] = WT + 0 * WSZ; p0.bias[0] = bq; p0.out[0] = q0;
    p0.A[1] = h;  p0.W[1] = WT + 1 * WSZ; p0.bias[1] = bk; p0.out[1] = k0;
    p0.A[2] = h;  p0.W[2] = WT + 2 * WSZ; p0.bias[2] = bv; p0.out[2] = v0;
    p0.A[3] = xb; p0.W[3] = WT + 3 * WSZ; p0.bias[3] = ba; p0.out[3] = a0;
    p0.A[4] = xb; p0.W[4] = WT + 4 * WSZ; p0.bias[4] = bb; p0.out[4] = b0;
    gemm_bf16<0><<<dim3(128, 8, 5), dim3(256), 0, stream>>>(p0, nullptr, nullptr);

    mid_fuse<<<dim3(MM / 4), dim3(256), 0, stream>>>(q0, k0, v0, a0, b0,
                                                     wcT, bqc, bkc, bvc, g2, u);

    GemmPtrs p1;
    for (int i = 0; i < 5; i++){ p1.A[i] = u; p1.W[i] = WT + 5 * WSZ; p1.bias[i] = bp; p1.out[i] = nullptr; }
    gemm_bf16<1><<<dim3(128, 8, 1), dim3(256), 0, stream>>>(p1, x, (float*)d_out);
}

// Round 5
// 571.423 us; speedup vs baseline: 1.0340x; 1.0002x over previous
//
#include <hip/hip_runtime.h>
#include <stdint.h>

#define DD 1024
#define TT 2048
#define BBATCH 8
#define MM (BBATCH*TT)   // 16384 rows

typedef unsigned short u16;
typedef unsigned int   u32;

typedef __attribute__((ext_vector_type(8))) __bf16 bf16x8;
typedef __attribute__((ext_vector_type(4))) float  floatx4;
typedef __attribute__((ext_vector_type(4))) unsigned short u16x4;
typedef __attribute__((ext_vector_type(8))) unsigned short u16x8;

__device__ __forceinline__ float b2f(u16 v){
    u32 x = ((u32)v) << 16;
    return __builtin_bit_cast(float, x);
}
__device__ __forceinline__ u16 f2b(float f){
    u32 u = __builtin_bit_cast(u32, f);
    u32 r = (u + 0x7fffu + ((u >> 16) & 1u)) >> 16;
    return (u16)r;
}
__device__ __forceinline__ float sigf(float x){
    return 1.0f / (1.0f + __expf(-x));
}
__device__ __forceinline__ float tanhfast(float x){
    float e = __expf(2.0f * x);          // inf for big x -> 1.0 (correct limit)
    return 1.0f - 2.0f / (e + 1.0f);
}

// async global->LDS, 16B per lane. LDS dest = wave-uniform base + lane*16.
__device__ __forceinline__ void g2l16(const u16* g, u16* l){
    __builtin_amdgcn_global_load_lds(
        (const __attribute__((address_space(1))) u32*)g,
        (__attribute__((address_space(3))) u32*)l, 16, 0, 0);
}

__device__ __forceinline__ void load16bf(const u16* p, float* o){
    u16x8 a = *(const u16x8*)p;
    u16x8 b = *(const u16x8*)(p + 8);
    #pragma unroll
    for (int j = 0; j < 8; j++) o[j]     = b2f(a[j]);
    #pragma unroll
    for (int j = 0; j < 8; j++) o[8 + j] = b2f(b[j]);
}

__device__ __forceinline__ void zero16(float* o){
    #pragma unroll
    for (int j = 0; j < 16; j++) o[j] = 0.f;
}

__device__ __forceinline__ void wave_reduce2(float& a, float& b){
    #pragma unroll
    for (int m = 32; m; m >>= 1){
        a += __shfl_xor(a, m, 64);
        b += __shfl_xor(b, m, 64);
    }
}

// ---------------- weight transpose: 6 x [1024,1024] fp32 -> bf16 [N,K] ----------------
__global__ __launch_bounds__(256) void transpose_w(
    const float* __restrict__ s0, const float* __restrict__ s1, const float* __restrict__ s2,
    const float* __restrict__ s3, const float* __restrict__ s4, const float* __restrict__ s5,
    u16* __restrict__ dst_base)
{
    __shared__ u16 tile[32][33];
    const float* srcs[6] = {s0, s1, s2, s3, s4, s5};
    const int z = blockIdx.z;
    const float* src = srcs[z];
    u16* dst = dst_base + (size_t)z * (DD * (size_t)DD);
    const int tx = threadIdx.x, ty = threadIdx.y;
    const int x = blockIdx.x * 32 + tx;
    #pragma unroll
    for (int i = 0; i < 4; i++){
        int y = blockIdx.y * 32 + ty + i * 8;
        tile[ty + i * 8][tx] = f2b(src[(size_t)y * DD + x]);
    }
    __syncthreads();
    const int x2 = blockIdx.y * 32 + tx;
    #pragma unroll
    for (int i = 0; i < 4; i++){
        int y2 = blockIdx.x * 32 + ty + i * 8;
        dst[(size_t)y2 * DD + x2] = tile[tx][ty + i * 8];
    }
}

// ---------------- conv-weight transpose: [1024,3] -> [3][1024], 3 streams ----------------
__global__ __launch_bounds__(256) void prep_wc(
    const float* __restrict__ w0, const float* __restrict__ w1, const float* __restrict__ w2,
    float* __restrict__ wcT)
{
    const float* srcs[3] = {w0, w1, w2};
    const int s = blockIdx.x / 3, tap = blockIdx.x % 3;
    #pragma unroll
    for (int i = 0; i < 4; i++){
        int d = threadIdx.x + i * 256;
        wcT[(s * 3 + tap) * DD + d] = srcs[s][d * 3 + tap];
    }
}

// ---------------- fused: x -> bf16 copy (xb) + zc_rms(x,g1) -> h; one row per wave ----------------
__global__ __launch_bounds__(256) void prep_rows(
    const float* __restrict__ in, const float* __restrict__ g,
    u16* __restrict__ xb, u16* __restrict__ h)
{
    const int tid = threadIdx.x;
    const int w = tid >> 6, lane = tid & 63;
    const int row = blockIdx.x * 4 + w;
    const int d0 = lane * 16;
    const size_t base = (size_t)row * DD + d0;

    float v[16];
    #pragma unroll
    for (int c = 0; c < 4; c++){
        floatx4 t = *(const floatx4*)(in + base + c * 4);
        v[c*4+0] = t.x; v[c*4+1] = t.y; v[c*4+2] = t.z; v[c*4+3] = t.w;
    }
    u16x8 x0, x1;
    #pragma unroll
    for (int j = 0; j < 8; j++){ x0[j] = f2b(v[j]); x1[j] = f2b(v[8+j]); }
    *(u16x8*)(xb + base)     = x0;
    *(u16x8*)(xb + base + 8) = x1;

    float s1 = 0.f, s2 = 0.f;
    #pragma unroll
    for (int j = 0; j < 16; j++){ s1 += v[j]; s2 += v[j]*v[j]; }
    wave_reduce2(s1, s2);
    const float mu = s1 * (1.0f / DD);
    const float ms = fmaxf(s2 * (1.0f / DD) - mu * mu, 0.0f);
    const float sc = rsqrtf(ms + 1e-8f);

    u16x8 o0, o1;
    #pragma unroll
    for (int j = 0; j < 8; j++)  o0[j] = f2b((v[j]     - mu) * sc * g[d0 + j]);
    #pragma unroll
    for (int j = 0; j < 8; j++)  o1[j] = f2b((v[8 + j] - mu) * sc * g[d0 + 8 + j]);
    *(u16x8*)(h + base)     = o0;
    *(u16x8*)(h + base + 8) = o1;
}

// ---------------- GEMM: C[M,N] = A[M,K](bf16) * W^T[N,K](bf16)^T + bias(fp32) ----------------
// BK=64, LDS layout [kk-half][row][32 u16] so ds_read bank pattern matches the
// BK=32 case (8-way, m97-normal) while halving barrier frequency.
struct GemmPtrs {
    const u16*   A[5];
    const u16*   W[5];     // transposed weights, [N,K] row-major, bf16
    const float* bias[5];
    u16*         out[5];
};

template<int MODE>   // 0: store bf16(A*W+bias) ; 1: fp32 epilogue with residual
__global__ __launch_bounds__(256) void gemm_bf16(
    GemmPtrs ptrs, const float* __restrict__ xres, float* __restrict__ dout)
{
    constexpr int BK = 64;
    __shared__ alignas(16) u16 As[128 * BK];   // 16 KB
    __shared__ alignas(16) u16 Bs[128 * BK];   // 16 KB

    const int z = blockIdx.z;
    const u16*   __restrict__ A    = ptrs.A[z];
    const u16*   __restrict__ W    = ptrs.W[z];
    const float* __restrict__ bias = ptrs.bias[z];
    u16* __restrict__ Cout = ptrs.out[z];

    const int tid  = threadIdx.x;
    const int wave = tid >> 6, lane = tid & 63;
    const int quad = lane >> 4, l16 = lane & 15;
    // XCD swizzle: bm fastest-varying so one A row-tile lives on one XCD's L2.
    const int bm = blockIdx.x * 128;
    const int bn = blockIdx.y * 128;
    const int wm = (wave & 1) * 64, wn = (wave >> 1) * 64;

    // staging: 1024 chunks of 16B per tile; slot=c stays LDS-contiguous (g2l16
    // requirement); source remapped so LDS = [kk=c>>9][row=(c>>2)&127][oct=c&3].
    const u16* ap[4];
    const u16* wp[4];
    #pragma unroll
    for (int t = 0; t < 4; t++){
        int c    = tid + t * 256;
        int kk   = c >> 9;
        int row  = (c >> 2) & 127;
        int oct  = c & 3;
        int koff = kk * 32 + oct * 8;
        ap[t] = A + (size_t)(bm + row) * DD + koff;
        wp[t] = W + (size_t)(bn + row) * DD + koff;
    }

    floatx4 acc[4][4];
    #pragma unroll
    for (int i = 0; i < 4; i++)
        #pragma unroll
        for (int j = 0; j < 4; j++)
            acc[i][j] = (floatx4){0.f, 0.f, 0.f, 0.f};

    for (int k0 = 0; k0 < DD; k0 += BK){
        #pragma unroll
        for (int t = 0; t < 4; t++){
            g2l16(ap[t] + k0, &As[(tid + t * 256) * 8]);
            g2l16(wp[t] + k0, &Bs[(tid + t * 256) * 8]);
        }
        __syncthreads();
        #pragma unroll
        for (int kk = 0; kk < 2; kk++){
            bf16x8 af[4], bfr[4];
            #pragma unroll
            for (int i = 0; i < 4; i++){
                af[i]  = *(const bf16x8*)&As[kk * 4096 + (wm + i * 16 + l16) * 32 + quad * 8];
                bfr[i] = *(const bf16x8*)&Bs[kk * 4096 + (wn + i * 16 + l16) * 32 + quad * 8];
            }
            #pragma unroll
            for (int i = 0; i < 4; i++)
                #pragma unroll
                for (int j = 0; j < 4; j++)
                    acc[i][j] = __builtin_amdgcn_mfma_f32_16x16x32_bf16(af[i], bfr[j], acc[i][j], 0, 0, 0);
        }
        __syncthreads();
    }

    float bj[4];
    #pragma unroll
    for (int j = 0; j < 4; j++) bj[j] = bias[bn + wn + j * 16 + l16];

    #pragma unroll
    for (int i = 0; i < 4; i++){
        const int rbase = bm + wm + i * 16 + quad * 4;
        #pragma unroll
        for (int j = 0; j < 4; j++){
            const int col = bn + wn + j * 16 + l16;
            #pragma unroll
            for (int r = 0; r < 4; r++){
                size_t idx = (size_t)(rbase + r) * DD + col;
                float zv = acc[i][j][r] + bj[j];
                if (MODE == 0){
                    Cout[idx] = f2b(zv);
                } else {
                    float sl = zv * sigf(zv);            // silu(dhat)
                    dout[idx] = xres[idx] + sigf(sl) * zv;
                }
            }
        }
    }
}

// ---------------- fused middle: one row per wave, no LDS / no syncthreads ----------------
__global__ __launch_bounds__(256) void mid_fuse(
    const u16* __restrict__ q0, const u16* __restrict__ k0, const u16* __restrict__ v0,
    const u16* __restrict__ a0, const u16* __restrict__ b0,
    const float* __restrict__ wcT,     // [3 streams][3 taps][1024]
    const float* __restrict__ bqc, const float* __restrict__ bkc, const float* __restrict__ bvc,
    const float* __restrict__ g2, u16* __restrict__ uout)
{
    const int tid  = threadIdx.x;
    const int w    = tid >> 6, lane = tid & 63;
    const int row  = blockIdx.x * 4 + w;
    const int t    = row & (TT - 1);
    const int d0   = lane * 16;
    const size_t base = (size_t)row * DD + d0;
    const bool hm = (t > 0), hp = (t < TT - 1);

    float q[16], k[16], v[16];
    {
        const u16*   srcs[3] = {q0, k0, v0};
        const float* bs[3]   = {bqc, bkc, bvc};
        float* outs[3]       = {q, k, v};
        #pragma unroll
        for (int s = 0; s < 3; s++){
            float cm[16], cc[16], cp[16];
            load16bf(srcs[s] + base, cc);
            if (hm) load16bf(srcs[s] + base - DD, cm);
            else    zero16(cm);
            if (hp) load16bf(srcs[s] + base + DD, cp);
            else    zero16(cp);
            const float* wt = wcT + s * 3 * DD + d0;
            const float* bb = bs[s] + d0;
            #pragma unroll
            for (int j = 0; j < 16; j++){
                float y = cm[j] * wt[j] + cc[j] * wt[DD + j] + cp[j] * wt[2 * DD + j] + bb[j];
                outs[s][j] = sigf(y);
            }
        }
    }

    float sq = 0.f, sk = 0.f;
    #pragma unroll
    for (int j = 0; j < 16; j++){ sq += q[j] * q[j]; sk += k[j] * k[j]; }
    wave_reduce2(sq, sk);
    const float rq = rsqrtf(sq + 1e-8f), rk = rsqrtf(sk + 1e-8f);

    float av[16], bv[16];
    load16bf(a0 + base, av);
    load16bf(b0 + base, bv);

    float dl[16], s1 = 0.f, s2 = 0.f;
    #pragma unroll
    for (int j = 0; j < 16; j++){
        float d = (q[j] * rq) * (k[j] * rk) * v[j];
        d = tanhfast(av[j]) * d + bv[j];
        dl[j] = d; s1 += d; s2 += d * d;
    }
    wave_reduce2(s1, s2);
    const float mu = s1 * (1.0f / DD);
    const float ms = fmaxf(s2 * (1.0f / DD) - mu * mu, 0.0f);
    const float sc = rsqrtf(ms + 1e-8f);

    u16x8 o0, o1;
    #pragma unroll
    for (int j = 0; j < 8; j++)  o0[j] = f2b((dl[j] - mu) * sc * g2[d0 + j]);
    #pragma unroll
    for (int j = 0; j < 8; j++)  o1[j] = f2b((dl[8 + j] - mu) * sc * g2[d0 + 8 + j]);
    *(u16x8*)(uout + base)     = o0;
    *(u16x8*)(uout + base + 8) = o1;
}

extern "C" void kernel_launch(void* const* d_in, const int* in_sizes, int n_in,
                              void* d_out, int out_size, void* d_ws, size_t ws_size,
                              hipStream_t stream)
{
    const float* x   = (const float*)d_in[0];
    const float* g1  = (const float*)d_in[1];
    const float* Wq  = (const float*)d_in[2];
    const float* bq  = (const float*)d_in[3];
    const float* Wk  = (const float*)d_in[4];
    const float* bk  = (const float*)d_in[5];
    const float* Wv  = (const float*)d_in[6];
    const float* bv  = (const float*)d_in[7];
    const float* wqc = (const float*)d_in[8];
    const float* bqc = (const float*)d_in[9];
    const float* wkc = (const float*)d_in[10];
    const float* bkc = (const float*)d_in[11];
    const float* wvc = (const float*)d_in[12];
    const float* bvc = (const float*)d_in[13];
    const float* Wa  = (const float*)d_in[14];
    const float* ba  = (const float*)d_in[15];
    const float* Wb  = (const float*)d_in[16];
    const float* bb  = (const float*)d_in[17];
    const float* g2  = (const float*)d_in[18];
    const float* Wp  = (const float*)d_in[19];
    const float* bp  = (const float*)d_in[20];

    u16* ws = (u16*)d_ws;
    const size_t WSZ = (size_t)DD * DD;      // 1M elements
    const size_t TSZ = (size_t)MM * DD;      // 16.78M elements
    u16* WT = ws;                             // 6 transposed bf16 weights (q,k,v,a,b,p)
    float* wcT = (float*)(ws + 6 * WSZ);      // 3*3*1024 fp32 conv weights, transposed
    u16* xb = ws + 6 * WSZ + 32768;           // bf16 copy of x (64KB gap holds wcT)
    u16* h  = xb + TSZ;
    u16* q0 = h  + TSZ;
    u16* k0 = q0 + TSZ;
    u16* v0 = k0 + TSZ;
    u16* a0 = v0 + TSZ;
    u16* b0 = a0 + TSZ;
    u16* u  = h;                              // h dead after GEMM stage; reuse for u

    transpose_w<<<dim3(32, 32, 6), dim3(32, 8, 1), 0, stream>>>(Wq, Wk, Wv, Wa, Wb, Wp, WT);
    prep_wc<<<dim3(9), dim3(256), 0, stream>>>(wqc, wkc, wvc, wcT);
    prep_rows<<<dim3(MM / 4), dim3(256), 0, stream>>>(x, g1, xb, h);

    GemmPtrs p0;
    p0.A[0] = h;  p0.W[0] = WT + 0 * WSZ; p0.bias[0] = bq; p0.out[0] = q0;
    p0.A[1] = h;  p0.W[1] = WT + 1 * WSZ; p0.bias[1] = bk; p0.out[1] = k0;
    p0.A[2] = h;  p0.W[2] = WT + 2 * WSZ; p0.bias[2] = bv; p0.out[2] = v0;
    p0.A[3] = xb; p0.W[3] = WT + 3 * WSZ; p0.bias[3] = ba; p0.out[3] = a0;
    p0.A[4] = xb; p0.W[4] = WT + 4 * WSZ; p0.bias[4] = bb; p0.out[4] = b0;
    gemm_bf16<0><<<dim3(128, 8, 5), dim3(256), 0, stream>>>(p0, nullptr, nullptr);

    mid_fuse<<<dim3(MM / 4), dim3(256), 0, stream>>>(q0, k0, v0, a0, b0,
                                                     wcT, bqc, bkc, bvc, g2, u);

    GemmPtrs p1;
    for (int i = 0; i < 5; i++){ p1.A[i] = u; p1.W[i] = WT + 5 * WSZ; p1.bias[i] = bp; p1.out[i] = nullptr; }
    gemm_bf16<1><<<dim3(128, 8, 1), dim3(256), 0, stream>>>(p1, x, (float*)d_out);
}

// Round 6
// 513.924 us; speedup vs baseline: 1.1497x; 1.1119x over previous
//
#include <hip/hip_runtime.h>
#include <stdint.h>

#define DD 1024
#define TT 2048
#define BBATCH 8
#define MM (BBATCH*TT)   // 16384 rows

typedef unsigned short u16;
typedef unsigned int   u32;

typedef __attribute__((ext_vector_type(8))) __bf16 bf16x8;
typedef __attribute__((ext_vector_type(4))) float  floatx4;
typedef __attribute__((ext_vector_type(4))) unsigned short u16x4;
typedef __attribute__((ext_vector_type(8))) unsigned short u16x8;

__device__ __forceinline__ float b2f(u16 v){
    u32 x = ((u32)v) << 16;
    return __builtin_bit_cast(float, x);
}
__device__ __forceinline__ u16 f2b(float f){
    u32 u = __builtin_bit_cast(u32, f);
    u32 r = (u + 0x7fffu + ((u >> 16) & 1u)) >> 16;
    return (u16)r;
}
__device__ __forceinline__ float sigf(float x){
    return 1.0f / (1.0f + __expf(-x));
}
__device__ __forceinline__ float tanhfast(float x){
    float e = __expf(2.0f * x);          // inf for big x -> 1.0 (correct limit)
    return 1.0f - 2.0f / (e + 1.0f);
}

// async global->LDS, 16B per lane. LDS dest = wave-uniform base + lane*16.
__device__ __forceinline__ void g2l16(const u16* g, u16* l){
    __builtin_amdgcn_global_load_lds(
        (const __attribute__((address_space(1))) u32*)g,
        (__attribute__((address_space(3))) u32*)l, 16, 0, 0);
}

__device__ __forceinline__ void load4bf(const u16* p, float* o){
    u16x4 v = *(const u16x4*)p;
    o[0] = b2f(v.x); o[1] = b2f(v.y); o[2] = b2f(v.z); o[3] = b2f(v.w);
}

__device__ __forceinline__ void wave_reduce2(float& a, float& b){
    #pragma unroll
    for (int m = 32; m; m >>= 1){
        a += __shfl_xor(a, m, 64);
        b += __shfl_xor(b, m, 64);
    }
}

// safe for repeated use: leading barrier protects red from the previous round
__device__ __forceinline__ void block_reduce2(float& a, float& b, float* red, int tid){
    #pragma unroll
    for (int off = 32; off; off >>= 1){
        a += __shfl_down(a, off, 64);
        b += __shfl_down(b, off, 64);
    }
    __syncthreads();
    if ((tid & 63) == 0){ red[tid >> 6] = a; red[4 + (tid >> 6)] = b; }
    __syncthreads();
    a = red[0] + red[1] + red[2] + red[3];
    b = red[4] + red[5] + red[6] + red[7];
}

// ---------------- weight transpose: 6 x [1024,1024] fp32 -> bf16 [N,K] ----------------
__global__ __launch_bounds__(256) void transpose_w(
    const float* __restrict__ s0, const float* __restrict__ s1, const float* __restrict__ s2,
    const float* __restrict__ s3, const float* __restrict__ s4, const float* __restrict__ s5,
    u16* __restrict__ dst_base)
{
    __shared__ u16 tile[32][33];
    const float* srcs[6] = {s0, s1, s2, s3, s4, s5};
    const int z = blockIdx.z;
    const float* src = srcs[z];
    u16* dst = dst_base + (size_t)z * (DD * (size_t)DD);
    const int tx = threadIdx.x, ty = threadIdx.y;
    const int x = blockIdx.x * 32 + tx;
    #pragma unroll
    for (int i = 0; i < 4; i++){
        int y = blockIdx.y * 32 + ty + i * 8;
        tile[ty + i * 8][tx] = f2b(src[(size_t)y * DD + x]);
    }
    __syncthreads();
    const int x2 = blockIdx.y * 32 + tx;
    #pragma unroll
    for (int i = 0; i < 4; i++){
        int y2 = blockIdx.x * 32 + ty + i * 8;
        dst[(size_t)y2 * DD + x2] = tile[tx][ty + i * 8];
    }
}

// ---------------- conv-weight transpose: [1024,3] -> [3][1024], 3 streams ----------------
__global__ __launch_bounds__(256) void prep_wc(
    const float* __restrict__ w0, const float* __restrict__ w1, const float* __restrict__ w2,
    float* __restrict__ wcT)
{
    const float* srcs[3] = {w0, w1, w2};
    const int s = blockIdx.x / 3, tap = blockIdx.x % 3;
    #pragma unroll
    for (int i = 0; i < 4; i++){
        int d = threadIdx.x + i * 256;
        wcT[(s * 3 + tap) * DD + d] = srcs[s][d * 3 + tap];
    }
}

// ---------------- fused: x -> bf16 copy (xb) + zc_rms(x,g1) -> h; one row per wave ----------------
__global__ __launch_bounds__(256) void prep_rows(
    const float* __restrict__ in, const float* __restrict__ g,
    u16* __restrict__ xb, u16* __restrict__ h)
{
    const int tid = threadIdx.x;
    const int w = tid >> 6, lane = tid & 63;
    const int row = blockIdx.x * 4 + w;
    const int d0 = lane * 16;
    const size_t base = (size_t)row * DD + d0;

    float v[16];
    #pragma unroll
    for (int c = 0; c < 4; c++){
        floatx4 t = *(const floatx4*)(in + base + c * 4);
        v[c*4+0] = t.x; v[c*4+1] = t.y; v[c*4+2] = t.z; v[c*4+3] = t.w;
    }
    u16x8 x0, x1;
    #pragma unroll
    for (int j = 0; j < 8; j++){ x0[j] = f2b(v[j]); x1[j] = f2b(v[8+j]); }
    *(u16x8*)(xb + base)     = x0;
    *(u16x8*)(xb + base + 8) = x1;

    float s1 = 0.f, s2 = 0.f;
    #pragma unroll
    for (int j = 0; j < 16; j++){ s1 += v[j]; s2 += v[j]*v[j]; }
    wave_reduce2(s1, s2);
    const float mu = s1 * (1.0f / DD);
    const float ms = fmaxf(s2 * (1.0f / DD) - mu * mu, 0.0f);
    const float sc = rsqrtf(ms + 1e-8f);

    u16x8 o0, o1;
    #pragma unroll
    for (int j = 0; j < 8; j++)  o0[j] = f2b((v[j]     - mu) * sc * g[d0 + j]);
    #pragma unroll
    for (int j = 0; j < 8; j++)  o1[j] = f2b((v[8 + j] - mu) * sc * g[d0 + 8 + j]);
    *(u16x8*)(h + base)     = o0;
    *(u16x8*)(h + base + 8) = o1;
}

// ---------------- GEMM: C[M,N] = A[M,K](bf16) * W^T[N,K](bf16)^T + bias(fp32) ----------------
// BK=32; LDS chunk placement XOR-swizzled: slot c holds source oct (c&3)^(row&3),
// so b128 fragment reads spread over 4 bank-quads (4-way) instead of 2 (8-way).
struct GemmPtrs {
    const u16*   A[5];
    const u16*   W[5];     // transposed weights, [N,K] row-major, bf16
    const float* bias[5];
    u16*         out[5];
};

template<int MODE>   // 0: store bf16(A*W+bias) ; 1: fp32 epilogue with residual
__global__ __launch_bounds__(256) void gemm_bf16(
    GemmPtrs ptrs, const float* __restrict__ xres, float* __restrict__ dout)
{
    constexpr int BK = 32;
    __shared__ alignas(16) u16 As[128 * BK];   // 8 KB
    __shared__ alignas(16) u16 Bs[128 * BK];   // 8 KB

    const int z = blockIdx.z;
    const u16*   __restrict__ A    = ptrs.A[z];
    const u16*   __restrict__ W    = ptrs.W[z];
    const float* __restrict__ bias = ptrs.bias[z];
    u16* __restrict__ Cout = ptrs.out[z];

    const int tid  = threadIdx.x;
    const int wave = tid >> 6, lane = tid & 63;
    const int quad = lane >> 4, l16 = lane & 15;
    // XCD swizzle: bm fastest-varying so one A row-tile lives on one XCD's L2.
    const int bm = blockIdx.x * 128;
    const int bn = blockIdx.y * 128;
    const int wm = (wave & 1) * 64, wn = (wave >> 1) * 64;

    // staging: 512 chunks of 16B per tile; slot c <- (row=c>>2, oct=(c&3)^(row&3))
    const int c0 = tid, c1 = tid + 256;
    const int r0 = c0 >> 2, o0s = ((c0 & 3) ^ (r0 & 3)) * 8;
    const int r1 = c1 >> 2, o1s = ((c1 & 3) ^ (r1 & 3)) * 8;
    const u16* a0p = A + (size_t)(bm + r0) * DD + o0s;
    const u16* a1p = A + (size_t)(bm + r1) * DD + o1s;
    const u16* w0p = W + (size_t)(bn + r0) * DD + o0s;
    const u16* w1p = W + (size_t)(bn + r1) * DD + o1s;

    floatx4 acc[4][4];
    #pragma unroll
    for (int i = 0; i < 4; i++)
        #pragma unroll
        for (int j = 0; j < 4; j++)
            acc[i][j] = (floatx4){0.f, 0.f, 0.f, 0.f};

    for (int k0 = 0; k0 < DD; k0 += BK){
        g2l16(a0p + k0, &As[c0 * 8]);
        g2l16(a1p + k0, &As[c1 * 8]);
        g2l16(w0p + k0, &Bs[c0 * 8]);
        g2l16(w1p + k0, &Bs[c1 * 8]);
        __syncthreads();
        bf16x8 af[4], bfr[4];
        #pragma unroll
        for (int i = 0; i < 4; i++){
            int ra = wm + i * 16 + l16;
            int rb = wn + i * 16 + l16;
            af[i]  = *(const bf16x8*)&As[(ra * 4 + (quad ^ (ra & 3))) * 8];
            bfr[i] = *(const bf16x8*)&Bs[(rb * 4 + (quad ^ (rb & 3))) * 8];
        }
        #pragma unroll
        for (int i = 0; i < 4; i++)
            #pragma unroll
            for (int j = 0; j < 4; j++)
                acc[i][j] = __builtin_amdgcn_mfma_f32_16x16x32_bf16(af[i], bfr[j], acc[i][j], 0, 0, 0);
        __syncthreads();
    }

    float bj[4];
    #pragma unroll
    for (int j = 0; j < 4; j++) bj[j] = bias[bn + wn + j * 16 + l16];

    #pragma unroll
    for (int i = 0; i < 4; i++){
        const int rbase = bm + wm + i * 16 + quad * 4;
        #pragma unroll
        for (int j = 0; j < 4; j++){
            const int col = bn + wn + j * 16 + l16;
            #pragma unroll
            for (int r = 0; r < 4; r++){
                size_t idx = (size_t)(rbase + r) * DD + col;
                float zv = acc[i][j][r] + bj[j];
                if (MODE == 0){
                    Cout[idx] = f2b(zv);
                } else {
                    float sl = zv * sigf(zv);            // silu(dhat)
                    dout[idx] = xres[idx] + sigf(sl) * zv;
                }
            }
        }
    }
}

// ---------------- fused middle: block per row, 4 elems/thread (VGPR-light) ----------------
__global__ __launch_bounds__(256) void mid_fuse(
    const u16* __restrict__ q0, const u16* __restrict__ k0, const u16* __restrict__ v0,
    const u16* __restrict__ a0, const u16* __restrict__ b0,
    const float* __restrict__ wcT,     // [3 streams][3 taps][1024]
    const float* __restrict__ bqc, const float* __restrict__ bkc, const float* __restrict__ bvc,
    const float* __restrict__ g2, u16* __restrict__ uout)
{
    __shared__ float red[8];
    const int row = blockIdx.x;
    const int t   = row & (TT - 1);
    const int tid = threadIdx.x;
    const int d0  = tid * 4;
    const size_t base = (size_t)row * DD + d0;
    const bool hm = (t > 0), hp = (t < TT - 1);

    float q[4], k[4], v[4];
    {
        const u16*   srcs[3] = {q0, k0, v0};
        const float* bs[3]   = {bqc, bkc, bvc};
        float* outs[3]       = {q, k, v};
        #pragma unroll
        for (int s = 0; s < 3; s++){
            float cm[4], cc[4], cp[4];
            load4bf(srcs[s] + base, cc);
            if (hm) load4bf(srcs[s] + base - DD, cm);
            else { cm[0]=0.f; cm[1]=0.f; cm[2]=0.f; cm[3]=0.f; }
            if (hp) load4bf(srcs[s] + base + DD, cp);
            else { cp[0]=0.f; cp[1]=0.f; cp[2]=0.f; cp[3]=0.f; }
            const float* wt = wcT + s * 3 * DD + d0;
            const float* bb = bs[s] + d0;
            #pragma unroll
            for (int j = 0; j < 4; j++){
                float y = cm[j] * wt[j] + cc[j] * wt[DD + j] + cp[j] * wt[2 * DD + j] + bb[j];
                outs[s][j] = sigf(y);
            }
        }
    }

    float sq = 0.f, sk = 0.f;
    #pragma unroll
    for (int j = 0; j < 4; j++){ sq += q[j] * q[j]; sk += k[j] * k[j]; }
    block_reduce2(sq, sk, red, tid);
    const float rq = rsqrtf(sq + 1e-8f), rk = rsqrtf(sk + 1e-8f);

    float av[4], bv[4];
    load4bf(a0 + base, av);
    load4bf(b0 + base, bv);

    float dl[4], s1 = 0.f, s2 = 0.f;
    #pragma unroll
    for (int j = 0; j < 4; j++){
        float d = (q[j] * rq) * (k[j] * rk) * v[j];
        d = tanhfast(av[j]) * d + bv[j];
        dl[j] = d; s1 += d; s2 += d * d;
    }
    block_reduce2(s1, s2, red, tid);
    const float mu = s1 * (1.0f / DD);
    const float ms = fmaxf(s2 * (1.0f / DD) - mu * mu, 0.0f);
    const float sc = rsqrtf(ms + 1e-8f);

    u16x4 ov;
    ov.x = f2b((dl[0] - mu) * sc * g2[d0 + 0]);
    ov.y = f2b((dl[1] - mu) * sc * g2[d0 + 1]);
    ov.z = f2b((dl[2] - mu) * sc * g2[d0 + 2]);
    ov.w = f2b((dl[3] - mu) * sc * g2[d0 + 3]);
    *(u16x4*)(uout + base) = ov;
}

extern "C" void kernel_launch(void* const* d_in, const int* in_sizes, int n_in,
                              void* d_out, int out_size, void* d_ws, size_t ws_size,
                              hipStream_t stream)
{
    const float* x   = (const float*)d_in[0];
    const float* g1  = (const float*)d_in[1];
    const float* Wq  = (const float*)d_in[2];
    const float* bq  = (const float*)d_in[3];
    const float* Wk  = (const float*)d_in[4];
    const float* bk  = (const float*)d_in[5];
    const float* Wv  = (const float*)d_in[6];
    const float* bv  = (const float*)d_in[7];
    const float* wqc = (const float*)d_in[8];
    const float* bqc = (const float*)d_in[9];
    const float* wkc = (const float*)d_in[10];
    const float* bkc = (const float*)d_in[11];
    const float* wvc = (const float*)d_in[12];
    const float* bvc = (const float*)d_in[13];
    const float* Wa  = (const float*)d_in[14];
    const float* ba  = (const float*)d_in[15];
    const float* Wb  = (const float*)d_in[16];
    const float* bb  = (const float*)d_in[17];
    const float* g2  = (const float*)d_in[18];
    const float* Wp  = (const float*)d_in[19];
    const float* bp  = (const float*)d_in[20];

    u16* ws = (u16*)d_ws;
    const size_t WSZ = (size_t)DD * DD;      // 1M elements
    const size_t TSZ = (size_t)MM * DD;      // 16.78M elements
    u16* WT = ws;                             // 6 transposed bf16 weights (q,k,v,a,b,p)
    float* wcT = (float*)(ws + 6 * WSZ);      // 3*3*1024 fp32 conv weights, transposed
    u16* xb = ws + 6 * WSZ + 32768;           // bf16 copy of x (64KB gap holds wcT)
    u16* h  = xb + TSZ;
    u16* q0 = h  + TSZ;
    u16* k0 = q0 + TSZ;
    u16* v0 = k0 + TSZ;
    u16* a0 = v0 + TSZ;
    u16* b0 = a0 + TSZ;
    u16* u  = h;                              // h dead after GEMM stage; reuse for u

    transpose_w<<<dim3(32, 32, 6), dim3(32, 8, 1), 0, stream>>>(Wq, Wk, Wv, Wa, Wb, Wp, WT);
    prep_wc<<<dim3(9), dim3(256), 0, stream>>>(wqc, wkc, wvc, wcT);
    prep_rows<<<dim3(MM / 4), dim3(256), 0, stream>>>(x, g1, xb, h);

    GemmPtrs p0;
    p0.A[0] = h;  p0.W[0] = WT + 0 * WSZ; p0.bias[0] = bq; p0.out[0] = q0;
    p0.A[1] = h;  p0.W[1] = WT + 1 * WSZ; p0.bias[1] = bk; p0.out[1] = k0;
    p0.A[2] = h;  p0.W[2] = WT + 2 * WSZ; p0.bias[2] = bv; p0.out[2] = v0;
    p0.A[3] = xb; p0.W[3] = WT + 3 * WSZ; p0.bias[3] = ba; p0.out[3] = a0;
    p0.A[4] = xb; p0.W[4] = WT + 4 * WSZ; p0.bias[4] = bb; p0.out[4] = b0;
    gemm_bf16<0><<<dim3(128, 8, 5), dim3(256), 0, stream>>>(p0, nullptr, nullptr);

    mid_fuse<<<dim3(MM), dim3(256), 0, stream>>>(q0, k0, v0, a0, b0,
                                                 wcT, bqc, bkc, bvc, g2, u);

    GemmPtrs p1;
    for (int i = 0; i < 5; i++){ p1.A[i] = u; p1.W[i] = WT + 5 * WSZ; p1.bias[i] = bp; p1.out[i] = nullptr; }
    gemm_bf16<1><<<dim3(128, 8, 1), dim3(256), 0, stream>>>(p1, x, (float*)d_out);
}